// Round 28
// baseline (70.982 us; speedup 1.0000x reference)
//
#include <hip/hip_runtime.h>
#include <math.h>
#include <stdint.h>

#define B_   4
#define C_   256
#define H_   64
#define W_   64
#define CC_  64
#define OE_  196
#define OH_  128
#define OW_  128
#define XH_  72    // padded height
#define NWB_ 10    // 80 padded cols / 8

typedef uint32_t u32;
typedef unsigned short u16;
typedef __attribute__((ext_vector_type(8))) short bf16x8;
typedef __attribute__((ext_vector_type(4))) float f32x4;
typedef __attribute__((ext_vector_type(4))) u32 u32x4;
typedef __attribute__((ext_vector_type(2))) u32 u32x2;

__device__ __forceinline__ u16 f2bf(float f) {
  u32 u = __builtin_bit_cast(u32, f);
  u32 r = (u + 0x7FFFu + ((u >> 16) & 1u)) >> 16;   // RNE
  return (u16)r;
}

// ------------------------------------------------------------------
// Kernel 0: weight re-layouts + h-halo-only xw8 zeroing (unchanged).
// ------------------------------------------------------------------
__global__ __launch_bounds__(256) void prep_weights(
    const float* __restrict__ w_comp, const float* __restrict__ w_enc,
    u16* __restrict__ wfrag, u16* __restrict__ wcf,
    u16* __restrict__ xw8) {
  int idx = blockIdx.x * 256 + threadIdx.x;    // 0..65535
  if (idx < 50 * 14 * 64) {
    int lane = idx & 63;
    int mt   = (idx >> 6) % 14;
    int ks   = idx / (14 * 64);
    int o    = mt * 16 + (lane & 15);
    int tap  = ks >> 1, s = ks & 1;
    int ky   = tap / 5, kx = tap % 5;
    int cb   = s * 32 + (lane >> 4) * 8;
    u32 pk[4];
    #pragma unroll
    for (int p = 0; p < 4; ++p) {
      u16 lo = 0, hi = 0;
      if (o < OE_) {
        lo = f2bf(w_enc[((o * CC_ + cb + 2 * p) * 5 + ky) * 5 + kx]);
        hi = f2bf(w_enc[((o * CC_ + cb + 2 * p + 1) * 5 + ky) * 5 + kx]);
      }
      pk[p] = (u32)lo | ((u32)hi << 16);
    }
    *reinterpret_cast<u32x4*>(wfrag + (size_t)idx * 8) =
        *reinterpret_cast<u32x4*>(pk);
  }
  if (idx < 8 * 4 * 64) {                      // wcf: 2048 chunks
    int lane = idx & 63;
    int mt   = (idx >> 6) & 3;
    int ks   = idx >> 8;
    int o    = mt * 16 + (lane & 15);
    int cb   = ks * 32 + (lane >> 4) * 8;
    u32 pk[4];
    #pragma unroll
    for (int p = 0; p < 4; ++p) {
      u16 lo = f2bf(w_comp[o * C_ + cb + 2 * p]);
      u16 hi = f2bf(w_comp[o * C_ + cb + 2 * p + 1]);
      pk[p] = (u32)lo | ((u32)hi << 16);
    }
    *reinterpret_cast<u32x4*>(wcf + (size_t)idx * 8) =
        *reinterpret_cast<u32x4*>(pk);
  }
  // ---- h-halo zeroing ----
  {
    u32x4 z = {0, 0, 0, 0};
    for (int i = idx; i < 81920; i += 65536) {
      int ck = i & 255, zi = i >> 8;
      int b = zi / 80, r = zi % 80;
      int hp8 = r / 10, wb = r % 10;
      int hp = (hp8 < 3) ? hp8 : 64 + hp8;
      *reinterpret_cast<u32x4*>(
          xw8 + (((size_t)(b * XH_ + hp)) * NWB_ + wb) * (C_ * 8) + ck * 8) = z;
    }
  }
}

// ------------------------------------------------------------------
// Kernel 1: 1x1 compressor via MFMA, wb-aligned (unchanged from R27).
// ------------------------------------------------------------------
__global__ __launch_bounds__(256) void compress_k(
    const float* __restrict__ x, const u16* __restrict__ wcf,
    const float* __restrict__ b_comp, u16* __restrict__ comp,
    u16* __restrict__ xw8) {
  __shared__ float xs[C_ * 25];   // 25,600 B
  int t   = threadIdx.x;
  int gid = blockIdx.x;           // bh*5 + wq
  int wq  = gid % 5;
  int bh  = gid / 5;
  int b = bh >> 6, h = bh & 63;
  int wbase = wq * 16 - 4;

  const float* xrow = x + (size_t)b * C_ * H_ * W_ + (size_t)h * W_;
  for (int i = t; i < 1280; i += 256) {
    int c = i / 5, q = i - (i / 5) * 5;
    int gw0 = wbase + q * 4;
    f32x4 v = {0.f, 0.f, 0.f, 0.f};
    if ((unsigned)gw0 < 61u)
      v = *reinterpret_cast<const f32x4*>(xrow + (size_t)c * H_ * W_ + gw0);
    float* r = xs + c * 25 + q * 4;
    r[0] = v[0]; r[1] = v[1]; r[2] = v[2]; r[3] = v[3];
  }
  __syncthreads();

  int wv   = __builtin_amdgcn_readfirstlane(t >> 6);
  int lane = t & 63;
  int i16  = lane & 15;
  int lg   = lane >> 4;

  bf16x8 af[8];
  #pragma unroll
  for (int ks = 0; ks < 8; ++ks)
    af[ks] = *reinterpret_cast<const bf16x8*>(
        wcf + (((size_t)ks * 4 + wv) * 64 + lane) * 8);

  f32x4 acc = {0.f, 0.f, 0.f, 0.f};
  #pragma unroll
  for (int ks = 0; ks < 8; ++ks) {
    short vv[8];
    #pragma unroll
    for (int j = 0; j < 8; ++j)
      vv[j] = (short)f2bf(xs[(ks * 32 + lg * 8 + j) * 25 + i16 + 1]);
    bf16x8 bf = (bf16x8){vv[0], vv[1], vv[2], vv[3], vv[4], vv[5], vv[6], vv[7]};
    acc = __builtin_amdgcn_mfma_f32_16x16x32_bf16(af[ks], bf, acc, 0, 0, 0);
  }

  {
    int w = wq * 16 - 3 + i16;
    if ((unsigned)w < (unsigned)W_) {
      int cc0 = wv * 16 + lg * 4;
      f32x4 bias = *reinterpret_cast<const f32x4*>(b_comp + cc0);
      u32 p0 = (u32)f2bf(acc[0] + bias[0]) | ((u32)f2bf(acc[1] + bias[1]) << 16);
      u32 p1 = (u32)f2bf(acc[2] + bias[2]) | ((u32)f2bf(acc[3] + bias[3]) << 16);
      u32x2 pk = {p0, p1};
      *reinterpret_cast<u32x2*>(comp + ((size_t)bh * 64 + w) * CC_ + cc0) = pk;
    }
  }

  {
    int c = t;
    size_t row = ((size_t)(b * XH_ + h + 3)) * NWB_;
    #pragma unroll
    for (int g = 0; g < 2; ++g) {
      int wb = wq * 2 + g;
      u32 pk[4];
      #pragma unroll
      for (int jp = 0; jp < 4; ++jp) {
        u16 lo = f2bf(xs[c * 25 + g * 8 + 1 + 2 * jp]);
        u16 hi = f2bf(xs[c * 25 + g * 8 + 2 + 2 * jp]);
        pk[jp] = (u32)lo | ((u32)hi << 16);
      }
      *reinterpret_cast<u32x4*>(xw8 + (row + wb) * (C_ * 8) + c * 8) =
          *reinterpret_cast<u32x4*>(pk);
    }
  }
}

// ------------------------------------------------------------------
// Kernel 2: encoder MFMA GEMM v11 — N=16 split for grid occupancy.
// Block = (b, h, wq 0..3): 16 pixels; grid 1024 = 4 blocks/CU x 8
// waves = 100% wave slots.  B-tile 5x20x64 bf16 (12.8KB); logits
// [224][20] f32 overlay (17.9KB LDS).  Per wave: 2 mt x 50 ks x
// 1 nt = 100 MFMA.  Banded-B epilogue: 64 threads, wg = wq*2+(px>>3).
// ------------------------------------------------------------------
#define ELG_ 17920   // max(12800 B-tile, 224*20*4 logits)

__device__ __forceinline__ void enc_lda(
    bf16x8 (&a)[2], const u16* __restrict__ wfrag,
    int ks, int mtbase, int lane) {
  #pragma unroll
  for (int mm = 0; mm < 2; ++mm)
    a[mm] = *reinterpret_cast<const bf16x8*>(
        wfrag + (((size_t)ks * 14 + mtbase + mm) * 64 + lane) * 8);
}

__device__ __forceinline__ void enc_step(
    int ks, const char* lds, const bf16x8 (&a)[2], f32x4 (&acc)[2],
    int nlane, int kq) {
  int tap = ks >> 1, s = ks & 1;
  int ky = tap / 5, kx = tap % 5;   // constants after full unroll
  int col = nlane + kx;             // 0..19
  int byte = (((ky * 20 + col) * 64 + s * 32 + kq * 8) * 2) ^ ((col & 7) << 4);
  bf16x8 bf = *reinterpret_cast<const bf16x8*>(lds + byte);
  #pragma unroll
  for (int mm = 0; mm < 2; ++mm)
    acc[mm] = __builtin_amdgcn_mfma_f32_16x16x32_bf16(a[mm], bf, acc[mm], 0, 0, 0);
}

__global__ __launch_bounds__(512) void enc_mfma_k(
    const u16* __restrict__ comp, const u16* __restrict__ wfrag,
    const float* __restrict__ b_enc, u16* __restrict__ bfrB) {
  __shared__ __align__(16) char lds[ELG_];

  int t   = threadIdx.x;                    // 0..511
  int bid = blockIdx.x;
  int swz = (bid & 7) * 128 + (bid >> 3);   // 1024 blocks, bijective
  int wq  = swz & 3;
  int bh  = swz >> 2;
  int b = bh >> 6, h = bh & 63;
  int w0 = wq * 16;

  // ---- stage B tile: 5 rows x 20 cols x 64 ch, XOR-swizzled ----
  {
    const u16* cbse = comp + (size_t)b * H_ * W_ * CC_;
    for (int i = t; i < 800; i += 512) {
      int q = i & 7, colr = i >> 3;
      int col = colr % 20, r = colr / 20;
      int hh = h - 2 + r, gw = w0 - 2 + col;
      u32x4 v = {0, 0, 0, 0};
      if ((unsigned)hh < H_ && (unsigned)gw < W_)
        v = *reinterpret_cast<const u32x4*>(cbse + ((size_t)hh * W_ + gw) * CC_ + q * 8);
      int byte = (((r * 20 + col) * 64 + q * 8) * 2) ^ ((col & 7) << 4);
      *reinterpret_cast<u32x4*>(lds + byte) = v;
    }
  }
  __syncthreads();   // B ready; no barriers in K-loop

  int wv    = __builtin_amdgcn_readfirstlane(t >> 6);   // 0..7
  int lane  = t & 63;
  int nlane = lane & 15, kq = lane >> 4;
  int mtbase = wv * 2;

  f32x4 acc[2];
  acc[0] = (f32x4){0.f, 0.f, 0.f, 0.f};
  acc[1] = (f32x4){0.f, 0.f, 0.f, 0.f};

  if (wv < 7) {
    bf16x8 abuf[4][2];
    #pragma unroll
    for (int p = 0; p < 4; ++p) enc_lda(abuf[p], wfrag, p, mtbase, lane);
    #pragma unroll
    for (int ks = 0; ks < 50; ++ks) {
      enc_step(ks, lds, abuf[ks & 3], acc, nlane, kq);
      if (ks < 46) enc_lda(abuf[ks & 3], wfrag, ks + 4, mtbase, lane);
    }
  }

  __syncthreads();
  float* lg = (float*)lds;
  if (wv < 7) {
    #pragma unroll
    for (int mm = 0; mm < 2; ++mm) {
      #pragma unroll
      for (int r = 0; r < 4; ++r) {
        int m = (mtbase + mm) * 16 + kq * 4 + r;
        lg[m * 20 + nlane] = acc[mm][r] + (m < OE_ ? b_enc[m] : 0.f);
      }
    }
  }
  __syncthreads();

  // ---- softmax (64 threads: 16 px x 4 rr) ----
  float v[49];
  float inv = 0.f;
  if (t < 64) {
    int px = t & 15, rr = t >> 4;
    float mx = -1e30f;
    #pragma unroll
    for (int n = 0; n < 49; ++n) {
      v[n] = lg[(4 * n + rr) * 20 + px];
      mx = fmaxf(mx, v[n]);
    }
    float sum = 0.f;
    #pragma unroll
    for (int n = 0; n < 49; ++n) { v[n] = __expf(v[n] - mx); sum += v[n]; }
    inv = 1.f / sum;
  }
  __syncthreads();   // lg reads done; lds reusable

  // ---- banded-B write in fragment layout ----
  if (t < 64) {
    int px = t & 15, rr = t >> 4;
    u16* sva = (u16*)lds;
    int myo = (px * 4 + rr) * 49;
    #pragma unroll
    for (int n = 0; n < 49; ++n) sva[myo + n] = f2bf(v[n] * inv);

    int wi = px & 7, wg = wq * 2 + (px >> 3);
    int p = rr >> 1, q = rr & 1;
    size_t bb = ((((size_t)(b * 64 + h) * 8 + wg) * 2 + p) * 4) * 512 +
                (size_t)(wi * 2 + q) * 8;
    #pragma unroll
    for (int ks = 0; ks < 4; ++ks) {
      #pragma unroll
      for (int lg2 = 0; lg2 < 4; ++lg2) {
        u32 pk[4];
        #pragma unroll
        for (int jp = 0; jp < 4; ++jp) {
          u16 e[2];
          #pragma unroll
          for (int u = 0; u < 2; ++u) {
            int j  = jp * 2 + u;
            int k  = ks * 32 + lg2 * 8 + j;
            int dy = k >> 4, dxp = k & 15;
            int dx = dxp - wi;
            bool ok = (dy < 7) && (dx >= 0) && (dx < 7);
            int idx = ok ? (dy * 7 + dx) : 0;
            u16 s = sva[myo + idx];
            e[u] = ok ? s : (u16)0;
          }
          pk[jp] = (u32)e[0] | ((u32)e[1] << 16);
        }
        *reinterpret_cast<u32x4*>(bfrB + bb + (size_t)ks * 512 + lg2 * 128) =
            *reinterpret_cast<u32x4*>(pk);
      }
    }
  }
}

// ------------------------------------------------------------------
// Kernel 3: CARAFE v24 (unchanged): zero-LDS, zero-barrier.
// ------------------------------------------------------------------
__device__ __forceinline__ void carafe_lda(
    bf16x8 (&buf)[4], const u16* __restrict__ xb,
    int c, int h, int wg, int lg) {
  #pragma unroll
  for (int ks = 0; ks < 4; ++ks) {
    int dy = ks * 2 + (lg >> 1);
    buf[ks] = *reinterpret_cast<const bf16x8*>(
        xb + (((size_t)(h + dy)) * NWB_ + wg + (lg & 1)) * (C_ * 8) + c * 8);
  }
}

__global__ __launch_bounds__(256) void carafe_k(
    const u16* __restrict__ xw8, const u16* __restrict__ bfrB,
    float* __restrict__ out) {
  int t   = threadIdx.x;
  int bid = blockIdx.x;                        // 2048 blocks
  int swz = (bid & 7) * 256 + (bid >> 3);      // bijective XCD chunk
  int mh  = swz & 1;
  int wgp = (swz >> 1) & 3;
  int h   = (swz >> 3) & 63;
  int b   = swz >> 9;

  int wv   = t >> 6;
  int lane = t & 63;
  int wg   = wgp * 2 + (wv & 1);
  int mq   = wv >> 1;
  int mt0  = mh * 8 + mq * 4;
  int col  = lane & 15;
  int lg   = lane >> 4;
  int mrow = lane & 15;
  int w0   = wg * 8;

  bf16x8 bfp[2][4];
  size_t bbase = (((size_t)(b * 64 + h) * 8 + wg) * 2) * 4 * 512;
  #pragma unroll
  for (int p = 0; p < 2; ++p)
    #pragma unroll
    for (int ks = 0; ks < 4; ++ks)
      bfp[p][ks] = *reinterpret_cast<const bf16x8*>(
          bfrB + bbase + (size_t)(p * 4 + ks) * 512 + lane * 8);

  const u16* xb = xw8 + (size_t)b * XH_ * NWB_ * (C_ * 8);
  bf16x8 bufA[4], bufB[4];
  carafe_lda(bufA, xb, mt0 * 16 + mrow, h, wg, lg);

  #pragma unroll
  for (int i = 0; i < 4; ++i) {
    int mt = mt0 + i;
    if (i < 3) {
      if (i & 1) carafe_lda(bufA, xb, (mt + 1) * 16 + mrow, h, wg, lg);
      else       carafe_lda(bufB, xb, (mt + 1) * 16 + mrow, h, wg, lg);
    }
    f32x4 acc0 = {0.f, 0.f, 0.f, 0.f};
    f32x4 acc1 = {0.f, 0.f, 0.f, 0.f};
    #pragma unroll
    for (int ks = 0; ks < 4; ++ks) {
      bf16x8 af = (i & 1) ? bufB[ks] : bufA[ks];
      acc0 = __builtin_amdgcn_mfma_f32_16x16x32_bf16(af, bfp[0][ks], acc0, 0, 0, 0);
      acc1 = __builtin_amdgcn_mfma_f32_16x16x32_bf16(af, bfp[1][ks], acc1, 0, 0, 0);
    }
    float* o0 = out +
        ((size_t)(b * C_ + mt * 16 + lg * 4) * OH_ + 2 * h) * OW_ + 2 * w0 + col;
    o0[0]                     = acc0[0];
    o0[(size_t)OH_ * OW_]     = acc0[1];
    o0[2 * (size_t)OH_ * OW_] = acc0[2];
    o0[3 * (size_t)OH_ * OW_] = acc0[3];
    float* o1 = o0 + OW_;
    o1[0]                     = acc1[0];
    o1[(size_t)OH_ * OW_]     = acc1[1];
    o1[2 * (size_t)OH_ * OW_] = acc1[2];
    o1[3 * (size_t)OH_ * OW_] = acc1[3];
  }
}

// ------------------------------------------------------------------
extern "C" void kernel_launch(void* const* d_in, const int* in_sizes, int n_in,
                              void* d_out, int out_size, void* d_ws, size_t ws_size,
                              hipStream_t stream) {
  const float* x      = (const float*)d_in[0];
  const float* w_comp = (const float*)d_in[1];
  const float* b_comp = (const float*)d_in[2];
  const float* w_enc  = (const float*)d_in[3];
  const float* b_enc  = (const float*)d_in[4];
  float* out = (float*)d_out;

  u16* bfrB  = (u16*)d_ws;                      // 8,388,608 bf16 (16MB)
  u16* wfrag = bfrB + 8388608;                  //   358,400 bf16
  u16* wcf   = wfrag + 358400;                  //    16,384 bf16
  u16* comp  = wcf + 16384;                     // 1,048,576 bf16
  u16* xw8   = comp + 1048576;                  // 5,898,240 bf16 (~31MB total)

  prep_weights<<<256, 256, 0, stream>>>(w_comp, w_enc, wfrag, wcf, xw8);
  compress_k<<<B_ * H_ * 5, 256, 0, stream>>>(x, wcf, b_comp, comp, xw8);
  enc_mfma_k<<<1024, 512, 0, stream>>>(comp, wfrag, b_enc, bfrB);
  carafe_k<<<2048, 256, 0, stream>>>(xw8, bfrB, out);
}

// Round 29
// 62.281 us; speedup vs baseline: 1.1397x; 1.1397x over previous
//
#include <hip/hip_runtime.h>
#include <math.h>
#include <stdint.h>

#define B_   4
#define C_   256
#define H_   64
#define W_   64
#define CC_  64
#define OE_  196
#define OH_  128
#define OW_  128
#define XH_  72    // padded height
#define NWB_ 10    // 80 padded cols / 8

typedef uint32_t u32;
typedef unsigned short u16;
typedef __attribute__((ext_vector_type(8))) short bf16x8;
typedef __attribute__((ext_vector_type(4))) float f32x4;
typedef __attribute__((ext_vector_type(4))) u32 u32x4;
typedef __attribute__((ext_vector_type(2))) u32 u32x2;

__device__ __forceinline__ u16 f2bf(float f) {
  u32 u = __builtin_bit_cast(u32, f);
  u32 r = (u + 0x7FFFu + ((u >> 16) & 1u)) >> 16;   // RNE
  return (u16)r;
}

// ------------------------------------------------------------------
// Kernel 0: weight re-layouts + h-halo-only xw8 zeroing (R27).
// ------------------------------------------------------------------
__global__ __launch_bounds__(256) void prep_weights(
    const float* __restrict__ w_comp, const float* __restrict__ w_enc,
    u16* __restrict__ wfrag, u16* __restrict__ wcf,
    u16* __restrict__ xw8) {
  int idx = blockIdx.x * 256 + threadIdx.x;    // 0..65535
  if (idx < 50 * 14 * 64) {
    int lane = idx & 63;
    int mt   = (idx >> 6) % 14;
    int ks   = idx / (14 * 64);
    int o    = mt * 16 + (lane & 15);
    int tap  = ks >> 1, s = ks & 1;
    int ky   = tap / 5, kx = tap % 5;
    int cb   = s * 32 + (lane >> 4) * 8;
    u32 pk[4];
    #pragma unroll
    for (int p = 0; p < 4; ++p) {
      u16 lo = 0, hi = 0;
      if (o < OE_) {
        lo = f2bf(w_enc[((o * CC_ + cb + 2 * p) * 5 + ky) * 5 + kx]);
        hi = f2bf(w_enc[((o * CC_ + cb + 2 * p + 1) * 5 + ky) * 5 + kx]);
      }
      pk[p] = (u32)lo | ((u32)hi << 16);
    }
    *reinterpret_cast<u32x4*>(wfrag + (size_t)idx * 8) =
        *reinterpret_cast<u32x4*>(pk);
  }
  if (idx < 8 * 4 * 64) {                      // wcf: 2048 chunks
    int lane = idx & 63;
    int mt   = (idx >> 6) & 3;
    int ks   = idx >> 8;
    int o    = mt * 16 + (lane & 15);
    int cb   = ks * 32 + (lane >> 4) * 8;
    u32 pk[4];
    #pragma unroll
    for (int p = 0; p < 4; ++p) {
      u16 lo = f2bf(w_comp[o * C_ + cb + 2 * p]);
      u16 hi = f2bf(w_comp[o * C_ + cb + 2 * p + 1]);
      pk[p] = (u32)lo | ((u32)hi << 16);
    }
    *reinterpret_cast<u32x4*>(wcf + (size_t)idx * 8) =
        *reinterpret_cast<u32x4*>(pk);
  }
  // ---- h-halo zeroing ----
  {
    u32x4 z = {0, 0, 0, 0};
    for (int i = idx; i < 81920; i += 65536) {
      int ck = i & 255, zi = i >> 8;
      int b = zi / 80, r = zi % 80;
      int hp8 = r / 10, wb = r % 10;
      int hp = (hp8 < 3) ? hp8 : 64 + hp8;
      *reinterpret_cast<u32x4*>(
          xw8 + (((size_t)(b * XH_ + hp)) * NWB_ + wb) * (C_ * 8) + ck * 8) = z;
    }
  }
}

// ------------------------------------------------------------------
// Kernel 1: 1x1 compressor via MFMA, wb-aligned (R27, unchanged).
// ------------------------------------------------------------------
__global__ __launch_bounds__(256) void compress_k(
    const float* __restrict__ x, const u16* __restrict__ wcf,
    const float* __restrict__ b_comp, u16* __restrict__ comp,
    u16* __restrict__ xw8) {
  __shared__ float xs[C_ * 25];   // 25,600 B
  int t   = threadIdx.x;
  int gid = blockIdx.x;           // bh*5 + wq
  int wq  = gid % 5;
  int bh  = gid / 5;
  int b = bh >> 6, h = bh & 63;
  int wbase = wq * 16 - 4;

  const float* xrow = x + (size_t)b * C_ * H_ * W_ + (size_t)h * W_;
  for (int i = t; i < 1280; i += 256) {
    int c = i / 5, q = i - (i / 5) * 5;
    int gw0 = wbase + q * 4;
    f32x4 v = {0.f, 0.f, 0.f, 0.f};
    if ((unsigned)gw0 < 61u)
      v = *reinterpret_cast<const f32x4*>(xrow + (size_t)c * H_ * W_ + gw0);
    float* r = xs + c * 25 + q * 4;
    r[0] = v[0]; r[1] = v[1]; r[2] = v[2]; r[3] = v[3];
  }
  __syncthreads();

  int wv   = __builtin_amdgcn_readfirstlane(t >> 6);
  int lane = t & 63;
  int i16  = lane & 15;
  int lg   = lane >> 4;

  bf16x8 af[8];
  #pragma unroll
  for (int ks = 0; ks < 8; ++ks)
    af[ks] = *reinterpret_cast<const bf16x8*>(
        wcf + (((size_t)ks * 4 + wv) * 64 + lane) * 8);

  f32x4 acc = {0.f, 0.f, 0.f, 0.f};
  #pragma unroll
  for (int ks = 0; ks < 8; ++ks) {
    short vv[8];
    #pragma unroll
    for (int j = 0; j < 8; ++j)
      vv[j] = (short)f2bf(xs[(ks * 32 + lg * 8 + j) * 25 + i16 + 1]);
    bf16x8 bf = (bf16x8){vv[0], vv[1], vv[2], vv[3], vv[4], vv[5], vv[6], vv[7]};
    acc = __builtin_amdgcn_mfma_f32_16x16x32_bf16(af[ks], bf, acc, 0, 0, 0);
  }

  {
    int w = wq * 16 - 3 + i16;
    if ((unsigned)w < (unsigned)W_) {
      int cc0 = wv * 16 + lg * 4;
      f32x4 bias = *reinterpret_cast<const f32x4*>(b_comp + cc0);
      u32 p0 = (u32)f2bf(acc[0] + bias[0]) | ((u32)f2bf(acc[1] + bias[1]) << 16);
      u32 p1 = (u32)f2bf(acc[2] + bias[2]) | ((u32)f2bf(acc[3] + bias[3]) << 16);
      u32x2 pk = {p0, p1};
      *reinterpret_cast<u32x2*>(comp + ((size_t)bh * 64 + w) * CC_ + cc0) = pk;
    }
  }

  {
    int c = t;
    size_t row = ((size_t)(b * XH_ + h + 3)) * NWB_;
    #pragma unroll
    for (int g = 0; g < 2; ++g) {
      int wb = wq * 2 + g;
      u32 pk[4];
      #pragma unroll
      for (int jp = 0; jp < 4; ++jp) {
        u16 lo = f2bf(xs[c * 25 + g * 8 + 1 + 2 * jp]);
        u16 hi = f2bf(xs[c * 25 + g * 8 + 2 + 2 * jp]);
        pk[jp] = (u32)lo | ((u32)hi << 16);
      }
      *reinterpret_cast<u32x4*>(xw8 + (row + wb) * (C_ * 8) + c * 8) =
          *reinterpret_cast<u32x4*>(pk);
    }
  }
}

// ------------------------------------------------------------------
// Kernel 2: encoder MFMA GEMM v12 — R27 structure (N=32, grid 512)
// with CHUNKED-BATCH A loads: 5 chunks x {20 b128 loads issued
// back-to-back, sched_barrier(0), 10 K-steps}.  One L2 latency per
// 10 steps instead of per step.  Occupancy is grid-limited (2
// blocks/CU) so the VGPR cost (~110) is free.
// ------------------------------------------------------------------
#define ELG_ 32256   // 224*36*4

__device__ __forceinline__ void enc_lda(
    bf16x8 (&a)[2], const u16* __restrict__ wfrag,
    int ks, int mtbase, int lane) {
  #pragma unroll
  for (int mm = 0; mm < 2; ++mm)
    a[mm] = *reinterpret_cast<const bf16x8*>(
        wfrag + (((size_t)ks * 14 + mtbase + mm) * 64 + lane) * 8);
}

__device__ __forceinline__ void enc_step(
    int ks, const char* lds, const bf16x8 (&a)[2], f32x4 (&acc)[2][2],
    int nlane, int kq) {
  int tap = ks >> 1, s = ks & 1;
  int ky = tap / 5, kx = tap % 5;   // constants after full unroll
  bf16x8 bf[2];
  #pragma unroll
  for (int nt = 0; nt < 2; ++nt) {
    int col = nt * 16 + nlane + kx;
    int byte = (((ky * 36 + col) * 64 + s * 32 + kq * 8) * 2) ^ ((col & 7) << 4);
    bf[nt] = *reinterpret_cast<const bf16x8*>(lds + byte);
  }
  #pragma unroll
  for (int mm = 0; mm < 2; ++mm)
    #pragma unroll
    for (int nt = 0; nt < 2; ++nt)
      acc[mm][nt] = __builtin_amdgcn_mfma_f32_16x16x32_bf16(
          a[mm], bf[nt], acc[mm][nt], 0, 0, 0);
}

__global__ __launch_bounds__(512) void enc_mfma_k(
    const u16* __restrict__ comp, const u16* __restrict__ wfrag,
    const float* __restrict__ b_enc, u16* __restrict__ bfrB) {
  __shared__ __align__(16) char lds[ELG_];

  int t   = threadIdx.x;                   // 0..511
  int bid = blockIdx.x;
  int swz = (bid & 7) * 64 + (bid >> 3);   // 512 blocks, bijective
  int wh  = swz & 1;
  int bh  = swz >> 1;
  int b = bh >> 6, h = bh & 63;
  int w0 = wh * 32;

  {
    const u16* cbse = comp + (size_t)b * H_ * W_ * CC_;
    for (int i = t; i < 1440; i += 512) {
      int q = i & 7, colr = i >> 3;
      int col = colr % 36, r = colr / 36;
      int hh = h - 2 + r, gw = w0 - 2 + col;
      u32x4 v = {0, 0, 0, 0};
      if ((unsigned)hh < H_ && (unsigned)gw < W_)
        v = *reinterpret_cast<const u32x4*>(cbse + ((size_t)hh * W_ + gw) * CC_ + q * 8);
      int byte = ((r * 36 + col) * 128 + q * 16) ^ ((col & 7) << 4);
      *reinterpret_cast<u32x4*>(lds + byte) = v;
    }
  }
  __syncthreads();

  int wv    = __builtin_amdgcn_readfirstlane(t >> 6);   // 0..7
  int lane  = t & 63;
  int nlane = lane & 15, kq = lane >> 4;
  int mtbase = wv * 2;

  f32x4 acc[2][2];
  #pragma unroll
  for (int mm = 0; mm < 2; ++mm)
    #pragma unroll
    for (int nt = 0; nt < 2; ++nt) acc[mm][nt] = (f32x4){0.f, 0.f, 0.f, 0.f};

  if (wv < 7) {
    #pragma unroll
    for (int ch = 0; ch < 5; ++ch) {
      bf16x8 ab[10][2];
      #pragma unroll
      for (int k = 0; k < 10; ++k)
        enc_lda(ab[k], wfrag, ch * 10 + k, mtbase, lane);
      __builtin_amdgcn_sched_barrier(0);   // pin load batch above compute
      #pragma unroll
      for (int k = 0; k < 10; ++k)
        enc_step(ch * 10 + k, lds, ab[k], acc, nlane, kq);
    }
  }

  __syncthreads();
  float* lg = (float*)lds;
  if (wv < 7) {
    #pragma unroll
    for (int mm = 0; mm < 2; ++mm) {
      #pragma unroll
      for (int nt = 0; nt < 2; ++nt) {
        #pragma unroll
        for (int r = 0; r < 4; ++r) {
          int m  = (mtbase + mm) * 16 + kq * 4 + r;
          int px = nt * 16 + nlane;
          lg[m * 36 + px] = acc[mm][nt][r] + (m < OE_ ? b_enc[m] : 0.f);
        }
      }
    }
  }
  __syncthreads();

  float v[49];
  float inv = 0.f;
  if (t < 128) {
    int px = t & 31, rr = t >> 5;
    float mx = -1e30f;
    #pragma unroll
    for (int n = 0; n < 49; ++n) {
      v[n] = lg[(4 * n + rr) * 36 + px];
      mx = fmaxf(mx, v[n]);
    }
    float sum = 0.f;
    #pragma unroll
    for (int n = 0; n < 49; ++n) { v[n] = __expf(v[n] - mx); sum += v[n]; }
    inv = 1.f / sum;
  }
  __syncthreads();

  if (t < 128) {
    int px = t & 31, rr = t >> 5;
    u16* sva = (u16*)lds;
    int myo = (px * 4 + rr) * 49;
    #pragma unroll
    for (int n = 0; n < 49; ++n) sva[myo + n] = f2bf(v[n] * inv);

    int wi = px & 7, wg = wh * 4 + (px >> 3);
    int p = rr >> 1, q = rr & 1;
    size_t bb = ((((size_t)(b * 64 + h) * 8 + wg) * 2 + p) * 4) * 512 +
                (size_t)(wi * 2 + q) * 8;
    #pragma unroll
    for (int ks = 0; ks < 4; ++ks) {
      #pragma unroll
      for (int lg2 = 0; lg2 < 4; ++lg2) {
        u32 pk[4];
        #pragma unroll
        for (int jp = 0; jp < 4; ++jp) {
          u16 e[2];
          #pragma unroll
          for (int u = 0; u < 2; ++u) {
            int j  = jp * 2 + u;
            int k  = ks * 32 + lg2 * 8 + j;
            int dy = k >> 4, dxp = k & 15;
            int dx = dxp - wi;
            bool ok = (dy < 7) && (dx >= 0) && (dx < 7);
            int idx = ok ? (dy * 7 + dx) : 0;
            u16 s = sva[myo + idx];
            e[u] = ok ? s : (u16)0;
          }
          pk[jp] = (u32)e[0] | ((u32)e[1] << 16);
        }
        *reinterpret_cast<u32x4*>(bfrB + bb + (size_t)ks * 512 + lg2 * 128) =
            *reinterpret_cast<u32x4*>(pk);
      }
    }
  }
}

// ------------------------------------------------------------------
// Kernel 3: CARAFE v24 (unchanged): zero-LDS, zero-barrier.
// ------------------------------------------------------------------
__device__ __forceinline__ void carafe_lda(
    bf16x8 (&buf)[4], const u16* __restrict__ xb,
    int c, int h, int wg, int lg) {
  #pragma unroll
  for (int ks = 0; ks < 4; ++ks) {
    int dy = ks * 2 + (lg >> 1);
    buf[ks] = *reinterpret_cast<const bf16x8*>(
        xb + (((size_t)(h + dy)) * NWB_ + wg + (lg & 1)) * (C_ * 8) + c * 8);
  }
}

__global__ __launch_bounds__(256) void carafe_k(
    const u16* __restrict__ xw8, const u16* __restrict__ bfrB,
    float* __restrict__ out) {
  int t   = threadIdx.x;
  int bid = blockIdx.x;                        // 2048 blocks
  int swz = (bid & 7) * 256 + (bid >> 3);      // bijective XCD chunk
  int mh  = swz & 1;
  int wgp = (swz >> 1) & 3;
  int h   = (swz >> 3) & 63;
  int b   = swz >> 9;

  int wv   = t >> 6;
  int lane = t & 63;
  int wg   = wgp * 2 + (wv & 1);
  int mq   = wv >> 1;
  int mt0  = mh * 8 + mq * 4;
  int col  = lane & 15;
  int lg   = lane >> 4;
  int mrow = lane & 15;
  int w0   = wg * 8;

  bf16x8 bfp[2][4];
  size_t bbase = (((size_t)(b * 64 + h) * 8 + wg) * 2) * 4 * 512;
  #pragma unroll
  for (int p = 0; p < 2; ++p)
    #pragma unroll
    for (int ks = 0; ks < 4; ++ks)
      bfp[p][ks] = *reinterpret_cast<const bf16x8*>(
          bfrB + bbase + (size_t)(p * 4 + ks) * 512 + lane * 8);

  const u16* xb = xw8 + (size_t)b * XH_ * NWB_ * (C_ * 8);
  bf16x8 bufA[4], bufB[4];
  carafe_lda(bufA, xb, mt0 * 16 + mrow, h, wg, lg);

  #pragma unroll
  for (int i = 0; i < 4; ++i) {
    int mt = mt0 + i;
    if (i < 3) {
      if (i & 1) carafe_lda(bufA, xb, (mt + 1) * 16 + mrow, h, wg, lg);
      else       carafe_lda(bufB, xb, (mt + 1) * 16 + mrow, h, wg, lg);
    }
    f32x4 acc0 = {0.f, 0.f, 0.f, 0.f};
    f32x4 acc1 = {0.f, 0.f, 0.f, 0.f};
    #pragma unroll
    for (int ks = 0; ks < 4; ++ks) {
      bf16x8 af = (i & 1) ? bufB[ks] : bufA[ks];
      acc0 = __builtin_amdgcn_mfma_f32_16x16x32_bf16(af, bfp[0][ks], acc0, 0, 0, 0);
      acc1 = __builtin_amdgcn_mfma_f32_16x16x32_bf16(af, bfp[1][ks], acc1, 0, 0, 0);
    }
    float* o0 = out +
        ((size_t)(b * C_ + mt * 16 + lg * 4) * OH_ + 2 * h) * OW_ + 2 * w0 + col;
    o0[0]                     = acc0[0];
    o0[(size_t)OH_ * OW_]     = acc0[1];
    o0[2 * (size_t)OH_ * OW_] = acc0[2];
    o0[3 * (size_t)OH_ * OW_] = acc0[3];
    float* o1 = o0 + OW_;
    o1[0]                     = acc1[0];
    o1[(size_t)OH_ * OW_]     = acc1[1];
    o1[2 * (size_t)OH_ * OW_] = acc1[2];
    o1[3 * (size_t)OH_ * OW_] = acc1[3];
  }
}

// ------------------------------------------------------------------
extern "C" void kernel_launch(void* const* d_in, const int* in_sizes, int n_in,
                              void* d_out, int out_size, void* d_ws, size_t ws_size,
                              hipStream_t stream) {
  const float* x      = (const float*)d_in[0];
  const float* w_comp = (const float*)d_in[1];
  const float* b_comp = (const float*)d_in[2];
  const float* w_enc  = (const float*)d_in[3];
  const float* b_enc  = (const float*)d_in[4];
  float* out = (float*)d_out;

  u16* bfrB  = (u16*)d_ws;                      // 8,388,608 bf16 (16MB)
  u16* wfrag = bfrB + 8388608;                  //   358,400 bf16
  u16* wcf   = wfrag + 358400;                  //    16,384 bf16
  u16* comp  = wcf + 16384;                     // 1,048,576 bf16
  u16* xw8   = comp + 1048576;                  // 5,898,240 bf16 (~31MB total)

  prep_weights<<<256, 256, 0, stream>>>(w_comp, w_enc, wfrag, wcf, xw8);
  compress_k<<<B_ * H_ * 5, 256, 0, stream>>>(x, wcf, b_comp, comp, xw8);
  enc_mfma_k<<<512, 512, 0, stream>>>(comp, wfrag, b_enc, bfrB);
  carafe_k<<<2048, 256, 0, stream>>>(xw8, bfrB, out);
}

// Round 30
// 61.511 us; speedup vs baseline: 1.1540x; 1.0125x over previous
//
#include <hip/hip_runtime.h>
#include <math.h>
#include <stdint.h>

#define B_   4
#define C_   256
#define H_   64
#define W_   64
#define CC_  64
#define OE_  196
#define OH_  128
#define OW_  128
#define XH_  72    // padded height
#define NWB_ 10    // 80 padded cols / 8

typedef uint32_t u32;
typedef unsigned short u16;
typedef __attribute__((ext_vector_type(8))) short bf16x8;
typedef __attribute__((ext_vector_type(4))) float f32x4;
typedef __attribute__((ext_vector_type(4))) u32 u32x4;
typedef __attribute__((ext_vector_type(2))) u32 u32x2;

__device__ __forceinline__ u16 f2bf(float f) {
  u32 u = __builtin_bit_cast(u32, f);
  u32 r = (u + 0x7FFFu + ((u >> 16) & 1u)) >> 16;   // RNE
  return (u16)r;
}

// ------------------------------------------------------------------
// Kernel 0: weight re-layouts + h-halo-only xw8 zeroing (R27).
// ------------------------------------------------------------------
__global__ __launch_bounds__(256) void prep_weights(
    const float* __restrict__ w_comp, const float* __restrict__ w_enc,
    u16* __restrict__ wfrag, u16* __restrict__ wcf,
    u16* __restrict__ xw8) {
  int idx = blockIdx.x * 256 + threadIdx.x;    // 0..65535
  if (idx < 50 * 14 * 64) {
    int lane = idx & 63;
    int mt   = (idx >> 6) % 14;
    int ks   = idx / (14 * 64);
    int o    = mt * 16 + (lane & 15);
    int tap  = ks >> 1, s = ks & 1;
    int ky   = tap / 5, kx = tap % 5;
    int cb   = s * 32 + (lane >> 4) * 8;
    u32 pk[4];
    #pragma unroll
    for (int p = 0; p < 4; ++p) {
      u16 lo = 0, hi = 0;
      if (o < OE_) {
        lo = f2bf(w_enc[((o * CC_ + cb + 2 * p) * 5 + ky) * 5 + kx]);
        hi = f2bf(w_enc[((o * CC_ + cb + 2 * p + 1) * 5 + ky) * 5 + kx]);
      }
      pk[p] = (u32)lo | ((u32)hi << 16);
    }
    *reinterpret_cast<u32x4*>(wfrag + (size_t)idx * 8) =
        *reinterpret_cast<u32x4*>(pk);
  }
  if (idx < 8 * 4 * 64) {                      // wcf: 2048 chunks
    int lane = idx & 63;
    int mt   = (idx >> 6) & 3;
    int ks   = idx >> 8;
    int o    = mt * 16 + (lane & 15);
    int cb   = ks * 32 + (lane >> 4) * 8;
    u32 pk[4];
    #pragma unroll
    for (int p = 0; p < 4; ++p) {
      u16 lo = f2bf(w_comp[o * C_ + cb + 2 * p]);
      u16 hi = f2bf(w_comp[o * C_ + cb + 2 * p + 1]);
      pk[p] = (u32)lo | ((u32)hi << 16);
    }
    *reinterpret_cast<u32x4*>(wcf + (size_t)idx * 8) =
        *reinterpret_cast<u32x4*>(pk);
  }
  // ---- h-halo zeroing ----
  {
    u32x4 z = {0, 0, 0, 0};
    for (int i = idx; i < 81920; i += 65536) {
      int ck = i & 255, zi = i >> 8;
      int b = zi / 80, r = zi % 80;
      int hp8 = r / 10, wb = r % 10;
      int hp = (hp8 < 3) ? hp8 : 64 + hp8;
      *reinterpret_cast<u32x4*>(
          xw8 + (((size_t)(b * XH_ + hp)) * NWB_ + wb) * (C_ * 8) + ck * 8) = z;
    }
  }
}

// ------------------------------------------------------------------
// Kernel 1: 1x1 compressor via MFMA, wb-aligned (R27, unchanged).
// ------------------------------------------------------------------
__global__ __launch_bounds__(256) void compress_k(
    const float* __restrict__ x, const u16* __restrict__ wcf,
    const float* __restrict__ b_comp, u16* __restrict__ comp,
    u16* __restrict__ xw8) {
  __shared__ float xs[C_ * 25];   // 25,600 B
  int t   = threadIdx.x;
  int gid = blockIdx.x;           // bh*5 + wq
  int wq  = gid % 5;
  int bh  = gid / 5;
  int b = bh >> 6, h = bh & 63;
  int wbase = wq * 16 - 4;

  const float* xrow = x + (size_t)b * C_ * H_ * W_ + (size_t)h * W_;
  for (int i = t; i < 1280; i += 256) {
    int c = i / 5, q = i - (i / 5) * 5;
    int gw0 = wbase + q * 4;
    f32x4 v = {0.f, 0.f, 0.f, 0.f};
    if ((unsigned)gw0 < 61u)
      v = *reinterpret_cast<const f32x4*>(xrow + (size_t)c * H_ * W_ + gw0);
    float* r = xs + c * 25 + q * 4;
    r[0] = v[0]; r[1] = v[1]; r[2] = v[2]; r[3] = v[3];
  }
  __syncthreads();

  int wv   = __builtin_amdgcn_readfirstlane(t >> 6);
  int lane = t & 63;
  int i16  = lane & 15;
  int lg   = lane >> 4;

  bf16x8 af[8];
  #pragma unroll
  for (int ks = 0; ks < 8; ++ks)
    af[ks] = *reinterpret_cast<const bf16x8*>(
        wcf + (((size_t)ks * 4 + wv) * 64 + lane) * 8);

  f32x4 acc = {0.f, 0.f, 0.f, 0.f};
  #pragma unroll
  for (int ks = 0; ks < 8; ++ks) {
    short vv[8];
    #pragma unroll
    for (int j = 0; j < 8; ++j)
      vv[j] = (short)f2bf(xs[(ks * 32 + lg * 8 + j) * 25 + i16 + 1]);
    bf16x8 bf = (bf16x8){vv[0], vv[1], vv[2], vv[3], vv[4], vv[5], vv[6], vv[7]};
    acc = __builtin_amdgcn_mfma_f32_16x16x32_bf16(af[ks], bf, acc, 0, 0, 0);
  }

  {
    int w = wq * 16 - 3 + i16;
    if ((unsigned)w < (unsigned)W_) {
      int cc0 = wv * 16 + lg * 4;
      f32x4 bias = *reinterpret_cast<const f32x4*>(b_comp + cc0);
      u32 p0 = (u32)f2bf(acc[0] + bias[0]) | ((u32)f2bf(acc[1] + bias[1]) << 16);
      u32 p1 = (u32)f2bf(acc[2] + bias[2]) | ((u32)f2bf(acc[3] + bias[3]) << 16);
      u32x2 pk = {p0, p1};
      *reinterpret_cast<u32x2*>(comp + ((size_t)bh * 64 + w) * CC_ + cc0) = pk;
    }
  }

  {
    int c = t;
    size_t row = ((size_t)(b * XH_ + h + 3)) * NWB_;
    #pragma unroll
    for (int g = 0; g < 2; ++g) {
      int wb = wq * 2 + g;
      u32 pk[4];
      #pragma unroll
      for (int jp = 0; jp < 4; ++jp) {
        u16 lo = f2bf(xs[c * 25 + g * 8 + 1 + 2 * jp]);
        u16 hi = f2bf(xs[c * 25 + g * 8 + 2 + 2 * jp]);
        pk[jp] = (u32)lo | ((u32)hi << 16);
      }
      *reinterpret_cast<u32x4*>(xw8 + (row + wb) * (C_ * 8) + c * 8) =
          *reinterpret_cast<u32x4*>(pk);
    }
  }
}

// ------------------------------------------------------------------
// Kernel 2: encoder MFMA GEMM v13 — R29 K-loop (chunked-batch A) +
// epilogue banded-B build/write SPREAD ACROSS ALL 512 THREADS
// (thread -> (px, rr, qt): builds only ks=qt quarter; 4 b128 stores
// per thread instead of 16 on a quarter of the threads).
// ------------------------------------------------------------------
#define ELG_ 32256   // 224*36*4

__device__ __forceinline__ void enc_lda(
    bf16x8 (&a)[2], const u16* __restrict__ wfrag,
    int ks, int mtbase, int lane) {
  #pragma unroll
  for (int mm = 0; mm < 2; ++mm)
    a[mm] = *reinterpret_cast<const bf16x8*>(
        wfrag + (((size_t)ks * 14 + mtbase + mm) * 64 + lane) * 8);
}

__device__ __forceinline__ void enc_step(
    int ks, const char* lds, const bf16x8 (&a)[2], f32x4 (&acc)[2][2],
    int nlane, int kq) {
  int tap = ks >> 1, s = ks & 1;
  int ky = tap / 5, kx = tap % 5;   // constants after full unroll
  bf16x8 bf[2];
  #pragma unroll
  for (int nt = 0; nt < 2; ++nt) {
    int col = nt * 16 + nlane + kx;
    int byte = (((ky * 36 + col) * 64 + s * 32 + kq * 8) * 2) ^ ((col & 7) << 4);
    bf[nt] = *reinterpret_cast<const bf16x8*>(lds + byte);
  }
  #pragma unroll
  for (int mm = 0; mm < 2; ++mm)
    #pragma unroll
    for (int nt = 0; nt < 2; ++nt)
      acc[mm][nt] = __builtin_amdgcn_mfma_f32_16x16x32_bf16(
          a[mm], bf[nt], acc[mm][nt], 0, 0, 0);
}

__global__ __launch_bounds__(512) void enc_mfma_k(
    const u16* __restrict__ comp, const u16* __restrict__ wfrag,
    const float* __restrict__ b_enc, u16* __restrict__ bfrB) {
  __shared__ __align__(16) char lds[ELG_];

  int t   = threadIdx.x;                   // 0..511
  int bid = blockIdx.x;
  int swz = (bid & 7) * 64 + (bid >> 3);   // 512 blocks, bijective
  int wh  = swz & 1;
  int bh  = swz >> 1;
  int b = bh >> 6, h = bh & 63;
  int w0 = wh * 32;

  {
    const u16* cbse = comp + (size_t)b * H_ * W_ * CC_;
    for (int i = t; i < 1440; i += 512) {
      int q = i & 7, colr = i >> 3;
      int col = colr % 36, r = colr / 36;
      int hh = h - 2 + r, gw = w0 - 2 + col;
      u32x4 v = {0, 0, 0, 0};
      if ((unsigned)hh < H_ && (unsigned)gw < W_)
        v = *reinterpret_cast<const u32x4*>(cbse + ((size_t)hh * W_ + gw) * CC_ + q * 8);
      int byte = ((r * 36 + col) * 128 + q * 16) ^ ((col & 7) << 4);
      *reinterpret_cast<u32x4*>(lds + byte) = v;
    }
  }
  __syncthreads();

  int wv    = __builtin_amdgcn_readfirstlane(t >> 6);   // 0..7
  int lane  = t & 63;
  int nlane = lane & 15, kq = lane >> 4;
  int mtbase = wv * 2;

  f32x4 acc[2][2];
  #pragma unroll
  for (int mm = 0; mm < 2; ++mm)
    #pragma unroll
    for (int nt = 0; nt < 2; ++nt) acc[mm][nt] = (f32x4){0.f, 0.f, 0.f, 0.f};

  if (wv < 7) {
    #pragma unroll
    for (int ch = 0; ch < 5; ++ch) {
      bf16x8 ab[10][2];
      #pragma unroll
      for (int k = 0; k < 10; ++k)
        enc_lda(ab[k], wfrag, ch * 10 + k, mtbase, lane);
      __builtin_amdgcn_sched_barrier(0);   // pin load batch above compute
      #pragma unroll
      for (int k = 0; k < 10; ++k)
        enc_step(ch * 10 + k, lds, ab[k], acc, nlane, kq);
    }
  }

  __syncthreads();
  float* lg = (float*)lds;
  if (wv < 7) {
    #pragma unroll
    for (int mm = 0; mm < 2; ++mm) {
      #pragma unroll
      for (int nt = 0; nt < 2; ++nt) {
        #pragma unroll
        for (int r = 0; r < 4; ++r) {
          int m  = (mtbase + mm) * 16 + kq * 4 + r;
          int px = nt * 16 + nlane;
          lg[m * 36 + px] = acc[mm][nt][r] + (m < OE_ ? b_enc[m] : 0.f);
        }
      }
    }
  }
  __syncthreads();

  // ---- softmax: 128 threads (px 0..31, rr 0..3) ----
  float v[49];
  float inv = 0.f;
  if (t < 128) {
    int px = t & 31, rr = t >> 5;
    float mx = -1e30f;
    #pragma unroll
    for (int n = 0; n < 49; ++n) {
      v[n] = lg[(4 * n + rr) * 36 + px];
      mx = fmaxf(mx, v[n]);
    }
    float sum = 0.f;
    #pragma unroll
    for (int n = 0; n < 49; ++n) { v[n] = __expf(v[n] - mx); sum += v[n]; }
    inv = 1.f / sum;
  }
  __syncthreads();   // lg reads done; lds reusable

  // ---- write normalized sv rows to LDS ----
  u16* sva = (u16*)lds;   // [32 px][4 rr][49]
  if (t < 128) {
    int px = t & 31, rr = t >> 5;
    int myo = (px * 4 + rr) * 49;
    #pragma unroll
    for (int n = 0; n < 49; ++n) sva[myo + n] = f2bf(v[n] * inv);
  }
  __syncthreads();

  // ---- banded-B write: ALL 512 threads; thread -> (px, rr, qt) ----
  {
    int px = t & 31, rr = (t >> 5) & 3, qt = t >> 7;   // qt = ks
    int myo = (px * 4 + rr) * 49;
    int wi = px & 7, wg = wh * 4 + (px >> 3);
    int p = rr >> 1, q = rr & 1;
    size_t bb = ((((size_t)(b * 64 + h) * 8 + wg) * 2 + p) * 4) * 512 +
                (size_t)(wi * 2 + q) * 8;
    int ks = qt;
    #pragma unroll
    for (int lg2 = 0; lg2 < 4; ++lg2) {
      u32 pk[4];
      #pragma unroll
      for (int jp = 0; jp < 4; ++jp) {
        u16 e[2];
        #pragma unroll
        for (int u = 0; u < 2; ++u) {
          int j  = jp * 2 + u;
          int k  = ks * 32 + lg2 * 8 + j;
          int dy = k >> 4, dxp = k & 15;
          int dx = dxp - wi;
          bool ok = (dy < 7) && (dx >= 0) && (dx < 7);
          int idx = ok ? (dy * 7 + dx) : 0;
          u16 s = sva[myo + idx];
          e[u] = ok ? s : (u16)0;
        }
        pk[jp] = (u32)e[0] | ((u32)e[1] << 16);
      }
      *reinterpret_cast<u32x4*>(bfrB + bb + (size_t)ks * 512 + lg2 * 128) =
          *reinterpret_cast<u32x4*>(pk);
    }
  }
}

// ------------------------------------------------------------------
// Kernel 3: CARAFE v24 (unchanged): zero-LDS, zero-barrier.
// ------------------------------------------------------------------
__device__ __forceinline__ void carafe_lda(
    bf16x8 (&buf)[4], const u16* __restrict__ xb,
    int c, int h, int wg, int lg) {
  #pragma unroll
  for (int ks = 0; ks < 4; ++ks) {
    int dy = ks * 2 + (lg >> 1);
    buf[ks] = *reinterpret_cast<const bf16x8*>(
        xb + (((size_t)(h + dy)) * NWB_ + wg + (lg & 1)) * (C_ * 8) + c * 8);
  }
}

__global__ __launch_bounds__(256) void carafe_k(
    const u16* __restrict__ xw8, const u16* __restrict__ bfrB,
    float* __restrict__ out) {
  int t   = threadIdx.x;
  int bid = blockIdx.x;                        // 2048 blocks
  int swz = (bid & 7) * 256 + (bid >> 3);      // bijective XCD chunk
  int mh  = swz & 1;
  int wgp = (swz >> 1) & 3;
  int h   = (swz >> 3) & 63;
  int b   = swz >> 9;

  int wv   = t >> 6;
  int lane = t & 63;
  int wg   = wgp * 2 + (wv & 1);
  int mq   = wv >> 1;
  int mt0  = mh * 8 + mq * 4;
  int col  = lane & 15;
  int lg   = lane >> 4;
  int mrow = lane & 15;
  int w0   = wg * 8;

  bf16x8 bfp[2][4];
  size_t bbase = (((size_t)(b * 64 + h) * 8 + wg) * 2) * 4 * 512;
  #pragma unroll
  for (int p = 0; p < 2; ++p)
    #pragma unroll
    for (int ks = 0; ks < 4; ++ks)
      bfp[p][ks] = *reinterpret_cast<const bf16x8*>(
          bfrB + bbase + (size_t)(p * 4 + ks) * 512 + lane * 8);

  const u16* xb = xw8 + (size_t)b * XH_ * NWB_ * (C_ * 8);
  bf16x8 bufA[4], bufB[4];
  carafe_lda(bufA, xb, mt0 * 16 + mrow, h, wg, lg);

  #pragma unroll
  for (int i = 0; i < 4; ++i) {
    int mt = mt0 + i;
    if (i < 3) {
      if (i & 1) carafe_lda(bufA, xb, (mt + 1) * 16 + mrow, h, wg, lg);
      else       carafe_lda(bufB, xb, (mt + 1) * 16 + mrow, h, wg, lg);
    }
    f32x4 acc0 = {0.f, 0.f, 0.f, 0.f};
    f32x4 acc1 = {0.f, 0.f, 0.f, 0.f};
    #pragma unroll
    for (int ks = 0; ks < 4; ++ks) {
      bf16x8 af = (i & 1) ? bufB[ks] : bufA[ks];
      acc0 = __builtin_amdgcn_mfma_f32_16x16x32_bf16(af, bfp[0][ks], acc0, 0, 0, 0);
      acc1 = __builtin_amdgcn_mfma_f32_16x16x32_bf16(af, bfp[1][ks], acc1, 0, 0, 0);
    }
    float* o0 = out +
        ((size_t)(b * C_ + mt * 16 + lg * 4) * OH_ + 2 * h) * OW_ + 2 * w0 + col;
    o0[0]                     = acc0[0];
    o0[(size_t)OH_ * OW_]     = acc0[1];
    o0[2 * (size_t)OH_ * OW_] = acc0[2];
    o0[3 * (size_t)OH_ * OW_] = acc0[3];
    float* o1 = o0 + OW_;
    o1[0]                     = acc1[0];
    o1[(size_t)OH_ * OW_]     = acc1[1];
    o1[2 * (size_t)OH_ * OW_] = acc1[2];
    o1[3 * (size_t)OH_ * OW_] = acc1[3];
  }
}

// ------------------------------------------------------------------
extern "C" void kernel_launch(void* const* d_in, const int* in_sizes, int n_in,
                              void* d_out, int out_size, void* d_ws, size_t ws_size,
                              hipStream_t stream) {
  const float* x      = (const float*)d_in[0];
  const float* w_comp = (const float*)d_in[1];
  const float* b_comp = (const float*)d_in[2];
  const float* w_enc  = (const float*)d_in[3];
  const float* b_enc  = (const float*)d_in[4];
  float* out = (float*)d_out;

  u16* bfrB  = (u16*)d_ws;                      // 8,388,608 bf16 (16MB)
  u16* wfrag = bfrB + 8388608;                  //   358,400 bf16
  u16* wcf   = wfrag + 358400;                  //    16,384 bf16
  u16* comp  = wcf + 16384;                     // 1,048,576 bf16
  u16* xw8   = comp + 1048576;                  // 5,898,240 bf16 (~31MB total)

  prep_weights<<<256, 256, 0, stream>>>(w_comp, w_enc, wfrag, wcf, xw8);
  compress_k<<<B_ * H_ * 5, 256, 0, stream>>>(x, wcf, b_comp, comp, xw8);
  enc_mfma_k<<<512, 512, 0, stream>>>(comp, wfrag, b_enc, bfrB);
  carafe_k<<<2048, 256, 0, stream>>>(xw8, bfrB, out);
}